// Round 2
// baseline (423.304 us; speedup 1.0000x reference)
//
#include <hip/hip_runtime.h>

typedef __attribute__((ext_vector_type(4))) short bf16x4;
typedef __attribute__((ext_vector_type(8))) short bf16x8;
typedef __attribute__((ext_vector_type(16))) float f32x16;
typedef __attribute__((ext_vector_type(4))) float f32x4;
typedef __attribute__((ext_vector_type(4))) unsigned int u32x4;

__device__ __forceinline__ unsigned short f2bf(float f) {
    unsigned int u = __builtin_bit_cast(unsigned int, f);
    u += 0x7fffu + ((u >> 16) & 1u);   // RNE (inputs are finite normals)
    return (unsigned short)(u >> 16);
}

#define PA 196   // lds_a pitch in bf16 elems

// GEMM: P[b] = feats[:, Kslice(b)] @ W[Kslice(b), :], feats built on the fly via Rtot.
// Block b owns p in [60b, 60b+60); 4 slabs (i,chunk); vk per slab = 3*64 (60 real + 4 pad per c3).
__global__ __launch_bounds__(1024) void gemm_kernel(
    const float* __restrict__ x,
    const float* __restrict__ rw, const float* __restrict__ sw, const float* __restrict__ cw,
    const float* __restrict__ W,
    const float* __restrict__ Rr, const float* __restrict__ Rs, const float* __restrict__ Rc,
    float* __restrict__ P)
{
    __shared__ unsigned short lds_a[256 * PA];      // 100352 B bf16 feats [n][vk]
    __shared__ unsigned int   lds_b[2][16 * 256];   // 2 x 16KB packed bf16 k-pairs [vk2][d]

    const int tid = threadIdx.x;
    const int blk = blockIdx.x;
    const int p0  = blk * 60;

    // ---- Rtot = (R_rotate*rw) @ (R_shear*sw) @ (R_scale*cw), row-major [c][d] ----
    float Ar[9], Br[9], Cr[9], T1[9], RT[9];
    #pragma unroll
    for (int e = 0; e < 9; ++e) { Ar[e] = Rr[e]*rw[e]; Br[e] = Rs[e]*sw[e]; Cr[e] = Rc[e]*cw[e]; }
    #pragma unroll
    for (int r = 0; r < 3; ++r)
        #pragma unroll
        for (int c = 0; c < 3; ++c)
            T1[r*3+c] = Ar[r*3+0]*Br[0*3+c] + Ar[r*3+1]*Br[1*3+c] + Ar[r*3+2]*Br[2*3+c];
    #pragma unroll
    for (int r = 0; r < 3; ++r)
        #pragma unroll
        for (int c = 0; c < 3; ++c)
            RT[r*3+c] = T1[r*3+0]*Cr[0*3+c] + T1[r*3+1]*Cr[1*3+c] + T1[r*3+2]*Cr[2*3+c];

    // ---- zero A pads once (cols c3*64+60..63); never overwritten (A-stage writes pl<60 only) ----
    if (tid < 256) {
        bf16x4 zz = (bf16x4)0;
        #pragma unroll
        for (int c3 = 0; c3 < 3; ++c3)
            *((bf16x4*)&lds_a[tid*PA + c3*64 + 60]) = zz;
    }

    const int w  = tid >> 6, l = tid & 63;
    const int lm = l & 31,  lh = l >> 5;
    const int m0 = (w >> 2) * 64;     // 4 wave-rows of 64
    const int d0 = (w & 3) * 64;      // 4 wave-cols of 64
    const int kp = tid >> 6;          // B-staging: k-pair id 0..15
    const int d4 = tid & 63;          // B-staging: d-group (4 floats)

    f32x16 acc[2][2];
    #pragma unroll
    for (int fm = 0; fm < 2; ++fm)
        #pragma unroll
        for (int fd = 0; fd < 2; ++fd)
            acc[fm][fd] = (f32x16)0.0f;

    for (int s = 0; s < 4; ++s) {
        const long kbase = (long)(s >> 1) * 90000 + (long)(s & 1) * 45000 + p0;
        const float* xs = x + kbase;

        // ---- prefetch W sub-tile 0 (one k-pair row-pair per thread, float4) ----
        f32x4 L0 = (f32x4)0.f, L1 = (f32x4)0.f;
        {
            int vk = kp * 2;                  // t=0: vk in [0,32)
            int c3 = vk >> 6, pl = vk & 63;   // pl even; pl<60 => pl+1<60 too
            if (pl < 60) {
                const float* wr = W + (kbase + (long)c3*15000 + pl)*256 + d4*4;
                L0 = *(const f32x4*)wr;
                L1 = *(const f32x4*)(wr + 256);
            }
        }

        // ---- A stage: 3840 items (n, p4); item loads 3x float4, writes 3x bf16x4 ----
        #pragma unroll
        for (int h = 0; h < 2; ++h) {
            f32x4 X[2][3];
            int nn[2], pp[2]; bool act[2];
            #pragma unroll
            for (int u = 0; u < 2; ++u) {
                int idx = (h*2 + u)*1024 + tid;
                act[u] = idx < 3840;
                int n = (int)(((unsigned)idx * 34953u) >> 19);   // idx/15, exact
                int p4 = idx - n*15;
                nn[u] = n; pp[u] = p4;
                if (act[u]) {
                    const float* px = xs + (long)n*180000 + p4*4;
                    X[u][0] = *(const f32x4*)px;
                    X[u][1] = *(const f32x4*)(px + 15000);
                    X[u][2] = *(const f32x4*)(px + 30000);
                }
            }
            #pragma unroll
            for (int u = 0; u < 2; ++u) {
                if (!act[u]) continue;
                bf16x4 o0, o1, o2;
                #pragma unroll
                for (int e = 0; e < 4; ++e) {
                    float x0 = X[u][0][e], x1 = X[u][1][e], x2 = X[u][2][e];
                    o0[e] = (short)f2bf(x0*RT[0] + x1*RT[3] + x2*RT[6]);
                    o1[e] = (short)f2bf(x0*RT[1] + x1*RT[4] + x2*RT[7]);
                    o2[e] = (short)f2bf(x0*RT[2] + x1*RT[5] + x2*RT[8]);
                }
                int a = nn[u]*PA + pp[u]*4;
                *((bf16x4*)&lds_a[a      ]) = o0;
                *((bf16x4*)&lds_a[a +  64]) = o1;
                *((bf16x4*)&lds_a[a + 128]) = o2;
            }
        }

        // ---- pack + write B sub-tile 0 (b128) ----
        {
            u32x4 bw;
            #pragma unroll
            for (int e = 0; e < 4; ++e)
                bw[e] = (unsigned int)f2bf(L0[e]) | ((unsigned int)f2bf(L1[e]) << 16);
            *((u32x4*)&lds_b[0][kp*256 + d4*4]) = bw;
        }
        __syncthreads();

        // ---- 6 sub-steps of 32 vk, B double-buffered ----
        for (int t = 0; t < 6; ++t) {
            f32x4 M0 = (f32x4)0.f, M1 = (f32x4)0.f;
            if (t < 5) {
                int vk = (t+1)*32 + kp*2;
                int c3 = vk >> 6, pl = vk & 63;
                if (pl < 60) {
                    const float* wr = W + (kbase + (long)c3*15000 + pl)*256 + d4*4;
                    M0 = *(const f32x4*)wr;
                    M1 = *(const f32x4*)(wr + 256);
                }
            }

            const unsigned int* bbuf = lds_b[t & 1];
            #pragma unroll
            for (int kk = 0; kk < 2; ++kk) {
                int kb = t*32 + kk*16 + lh*8;
                bf16x8 af[2];
                #pragma unroll
                for (int fm = 0; fm < 2; ++fm) {
                    const unsigned short* pa = &lds_a[(m0 + fm*32 + lm)*PA + kb];
                    bf16x4 alo = *(const bf16x4*)pa;
                    bf16x4 ahi = *(const bf16x4*)(pa + 4);
                    af[fm] = __builtin_shufflevector(alo, ahi, 0,1,2,3,4,5,6,7);
                }
                #pragma unroll
                for (int fd = 0; fd < 2; ++fd) {
                    int db = d0 + fd*32 + lm;
                    int v2 = kk*8 + lh*4;
                    u32x4 bwv = { bbuf[(v2+0)*256 + db], bbuf[(v2+1)*256 + db],
                                  bbuf[(v2+2)*256 + db], bbuf[(v2+3)*256 + db] };
                    bf16x8 bfv = __builtin_bit_cast(bf16x8, bwv);
                    #pragma unroll
                    for (int fm = 0; fm < 2; ++fm)
                        acc[fm][fd] = __builtin_amdgcn_mfma_f32_32x32x16_bf16(af[fm], bfv, acc[fm][fd], 0, 0, 0);
                }
            }

            if (t < 5) {
                u32x4 bw;
                #pragma unroll
                for (int e = 0; e < 4; ++e)
                    bw[e] = (unsigned int)f2bf(M0[e]) | ((unsigned int)f2bf(M1[e]) << 16);
                *((u32x4*)&lds_b[(t+1) & 1][kp*256 + d4*4]) = bw;
            }
            __syncthreads();
        }
    }

    // ---- write fp32 partial C tile ----
    float* Pb = P + (size_t)blk * 65536;
    #pragma unroll
    for (int fm = 0; fm < 2; ++fm)
        #pragma unroll
        for (int fd = 0; fd < 2; ++fd)
            #pragma unroll
            for (int r = 0; r < 16; ++r) {
                int row = m0 + fm*32 + (r & 3) + 8*(r >> 2) + 4*lh;
                int col = d0 + fd*32 + lm;
                Pb[row*256 + col] = acc[fm][fd][r];
            }
}

// Sum 250 partials + bias -> z (written twice to out), zhat -> Z. One block per n.
__global__ __launch_bounds__(512) void reduce_kernel(
    const float* __restrict__ P, const float* __restrict__ bias,
    float* __restrict__ out, float* __restrict__ Z)
{
    __shared__ f32x4 sred[8][64];
    const int n = blockIdx.x;
    const int tid = threadIdx.x;
    const int d4 = tid & 63, sg = tid >> 6;

    const f32x4* p = (const f32x4*)(P + (size_t)n * 256) + d4;
    f32x4 z = (f32x4)0.f;
    #pragma unroll 8
    for (int s = sg; s < 250; s += 8) z += p[(size_t)s * 16384];
    sred[sg][d4] = z;
    __syncthreads();

    if (tid < 64) {
        f32x4 zf = sred[0][tid];
        #pragma unroll
        for (int g = 1; g < 8; ++g) zf += sred[g][tid];
        zf += ((const f32x4*)bias)[tid];
        // out is offset by 1 (loss scalar) -> only 4B-aligned: scalar stores
        float* o1 = out + 1 + n*256 + tid*4;
        float* o2 = o1 + 65536;
        #pragma unroll
        for (int e = 0; e < 4; ++e) { o1[e] = zf[e]; o2[e] = zf[e]; }
        float sq = zf[0]*zf[0] + zf[1]*zf[1] + zf[2]*zf[2] + zf[3]*zf[3];
        #pragma unroll
        for (int off = 32; off > 0; off >>= 1) sq += __shfl_xor(sq, off, 64);
        float inv = rsqrtf(sq);
        ((f32x4*)Z)[n*64 + tid] = zf * inv;
    }
}

// loss = 2 - (2/255)*(||S||^2/256 - 1), S = sum_n zhat_n
__global__ __launch_bounds__(1024) void loss_kernel(const float* __restrict__ Z, float* __restrict__ out)
{
    __shared__ f32x4 sp[16][64];
    const int tid = threadIdx.x;
    const int c4 = tid & 63, g = tid >> 6;
    f32x4 S = (f32x4)0.f;
    #pragma unroll 4
    for (int n = g; n < 256; n += 16) S += ((const f32x4*)Z)[n*64 + c4];
    sp[g][c4] = S;
    __syncthreads();
    if (tid < 64) {
        f32x4 T = sp[0][tid];
        #pragma unroll
        for (int gg = 1; gg < 16; ++gg) T += sp[gg][tid];
        float v = T[0]*T[0] + T[1]*T[1] + T[2]*T[2] + T[3]*T[3];
        #pragma unroll
        for (int off = 32; off > 0; off >>= 1) v += __shfl_xor(v, off, 64);
        if (tid == 0)
            out[0] = 2.0f - (2.0f / 255.0f) * (v * (1.0f / 256.0f) - 1.0f);
    }
}

extern "C" void kernel_launch(void* const* d_in, const int* in_sizes, int n_in,
                              void* d_out, int out_size, void* d_ws, size_t ws_size,
                              hipStream_t stream)
{
    (void)in_sizes; (void)n_in; (void)out_size; (void)ws_size;
    const float* x  = (const float*)d_in[0];
    const float* rw = (const float*)d_in[1];
    const float* sw = (const float*)d_in[2];
    const float* cw = (const float*)d_in[3];
    const float* W  = (const float*)d_in[4];
    const float* bb = (const float*)d_in[5];
    const float* Rr = (const float*)d_in[6];
    const float* Rs = (const float*)d_in[7];
    const float* Rc = (const float*)d_in[8];
    float* out = (float*)d_out;
    float* P = (float*)d_ws;                        // 250 * 65536 fp32 partials
    float* Z = P + (size_t)250 * 65536;             // 65536 fp32 zhat

    gemm_kernel<<<250, 1024, 0, stream>>>(x, rw, sw, cw, W, Rr, Rs, Rc, P);
    reduce_kernel<<<256, 512, 0, stream>>>(P, bb, out, Z);
    loss_kernel<<<1, 1024, 0, stream>>>(Z, out);
}